// Round 1
// baseline (252.478 us; speedup 1.0000x reference)
//
#include <hip/hip_runtime.h>
#include <hip/hip_bf16.h>

#define Bn 16
#define Nn 256
#define Tn 96
#define Hn 128
#define EPSf 1e-5f

// ---------------------------------------------------------------------------
// Precompute kernel: builds three small matrices into workspace.
//   M [Tn x Hn]  = Wp @ W1                       (W1 = Wf[0:128])
//   E [Nn x Hn]  = node_emb @ W2 + bp @ W1       (W2 = Wf[128:256])
//   Ct[Tn x Hn]  = time_emb @ W3 + bf            (W3 = Wf[256:384])
// grid = Tn + Nn + Tn = 448 blocks, block = 128 threads (thread k = out col).
// ---------------------------------------------------------------------------
__global__ __launch_bounds__(128) void precompute_kernel(
    const float* __restrict__ Wp, const float* __restrict__ bp,
    const float* __restrict__ Wf, const float* __restrict__ bf,
    const float* __restrict__ node_emb, const float* __restrict__ time_emb,
    float* __restrict__ M, float* __restrict__ E, float* __restrict__ Ct) {
  __shared__ float row[Hn];
  const int k = threadIdx.x;
  const int bid = blockIdx.x;
  if (bid < Tn) {
    const int t = bid;
    row[k] = Wp[t * Hn + k];
    __syncthreads();
    float acc = 0.f;
#pragma unroll 8
    for (int h = 0; h < Hn; ++h) acc = fmaf(row[h], Wf[h * Hn + k], acc);
    M[t * Hn + k] = acc;
  } else if (bid < Tn + Nn) {
    const int n = bid - Tn;
    row[k] = node_emb[n * Hn + k];
    __syncthreads();
    float acc = 0.f;
#pragma unroll 8
    for (int h = 0; h < Hn; ++h) acc = fmaf(row[h], Wf[(Hn + h) * Hn + k], acc);
    __syncthreads();
    row[k] = bp[k];
    __syncthreads();
#pragma unroll 8
    for (int h = 0; h < Hn; ++h) acc = fmaf(row[h], Wf[h * Hn + k], acc);
    E[n * Hn + k] = acc;
  } else {
    const int t = bid - Tn - Nn;
    row[k] = time_emb[t * Hn + k];
    __syncthreads();
    float acc = bf[k];
#pragma unroll 8
    for (int h = 0; h < Hn; ++h) acc = fmaf(row[h], Wf[(2 * Hn + h) * Hn + k], acc);
    Ct[t * Hn + k] = acc;
  }
}

// ---------------------------------------------------------------------------
// Main kernel: one block per (b,n). Computes A row = x_row @ M + E[n] in LDS,
// then each wave handles t-rows: h = relu(A + Ct[t]); LayerNorm over H=128
// via in-wave shuffle reduction (lane holds float2); coalesced float2 stores.
// Memory-bound on the 201 MB output write.
// ---------------------------------------------------------------------------
__global__ __launch_bounds__(256) void main_kernel(
    const float* __restrict__ x, const float* __restrict__ M,
    const float* __restrict__ E, const float* __restrict__ Ct,
    const float* __restrict__ gamma, const float* __restrict__ beta,
    float* __restrict__ out) {
  const int bn = blockIdx.x;        // b*N + n
  const int n = bn & (Nn - 1);      // N = 256 (pow2)
  __shared__ float xs[Tn];
  __shared__ float as[Hn];
  const int tid = threadIdx.x;

  if (tid < Tn) xs[tid] = x[bn * Tn + tid];
  __syncthreads();
  if (tid < Hn) {
    float acc = E[n * Hn + tid];
#pragma unroll 8
    for (int t = 0; t < Tn; ++t) acc = fmaf(xs[t], M[t * Hn + tid], acc);
    as[tid] = acc;
  }
  __syncthreads();

  const int wave = tid >> 6;
  const int lane = tid & 63;
  const float2 a  = *(const float2*)&as[lane * 2];
  const float2 g  = *(const float2*)&gamma[lane * 2];
  const float2 bt = *(const float2*)&beta[lane * 2];
  const float inv128 = 1.f / 128.f;

  for (int t = wave; t < Tn; t += 4) {
    const float2 c = *(const float2*)&Ct[t * Hn + lane * 2];
    const float h0 = fmaxf(a.x + c.x, 0.f);
    const float h1 = fmaxf(a.y + c.y, 0.f);
    float s  = h0 + h1;
    float ss = fmaf(h0, h0, h1 * h1);
#pragma unroll
    for (int off = 32; off > 0; off >>= 1) {
      s  += __shfl_xor(s,  off, 64);
      ss += __shfl_xor(ss, off, 64);
    }
    const float mean = s * inv128;
    const float var  = fmaf(-mean, mean, ss * inv128);
    const float inv  = rsqrtf(var + EPSf);
    float2 o;
    o.x = fmaf((h0 - mean) * inv, g.x, bt.x);
    o.y = fmaf((h1 - mean) * inv, g.y, bt.y);
    *(float2*)&out[((size_t)bn * Tn + t) * Hn + lane * 2] = o;
  }
}

extern "C" void kernel_launch(void* const* d_in, const int* in_sizes, int n_in,
                              void* d_out, int out_size, void* d_ws, size_t ws_size,
                              hipStream_t stream) {
  const float* x        = (const float*)d_in[0];
  const float* Wp       = (const float*)d_in[1];
  const float* bp       = (const float*)d_in[2];
  const float* Wf       = (const float*)d_in[3];
  const float* bf       = (const float*)d_in[4];
  const float* gamma    = (const float*)d_in[5];
  const float* beta     = (const float*)d_in[6];
  const float* node_emb = (const float*)d_in[7];
  const float* time_emb = (const float*)d_in[8];
  float* out = (float*)d_out;

  // Workspace layout (floats): M[96*128] | E[256*128] | Ct[96*128]  (~229 KB)
  float* ws = (float*)d_ws;
  float* M  = ws;
  float* E  = ws + Tn * Hn;
  float* Ct = ws + Tn * Hn + Nn * Hn;

  precompute_kernel<<<Tn + Nn + Tn, 128, 0, stream>>>(Wp, bp, Wf, bf, node_emb,
                                                      time_emb, M, E, Ct);
  main_kernel<<<Bn * Nn, 256, 0, stream>>>(x, M, E, Ct, gamma, beta, out);
}

// Round 2
// 232.708 us; speedup vs baseline: 1.0850x; 1.0850x over previous
//
#include <hip/hip_runtime.h>
#include <hip/hip_bf16.h>

#define Bn 16
#define Nn 256
#define Tn 96
#define Hn 128
#define EPSf 1e-5f

// ---------------------------------------------------------------------------
// Precompute kernel: builds three small matrices into workspace.
//   M [Tn x Hn]  = Wp @ W1                       (W1 = Wf[0:128])
//   E [Nn x Hn]  = node_emb @ W2 + bp @ W1       (W2 = Wf[128:256])
//   Ct[Tn x Hn]  = time_emb @ W3 + bf            (W3 = Wf[256:384])
// grid = Tn + Nn + Tn = 448 blocks, block = 128 threads (thread k = out col).
// ---------------------------------------------------------------------------
__global__ __launch_bounds__(128) void precompute_kernel(
    const float* __restrict__ Wp, const float* __restrict__ bp,
    const float* __restrict__ Wf, const float* __restrict__ bf,
    const float* __restrict__ node_emb, const float* __restrict__ time_emb,
    float* __restrict__ M, float* __restrict__ E, float* __restrict__ Ct) {
  __shared__ float row[Hn];
  const int k = threadIdx.x;
  const int bid = blockIdx.x;
  if (bid < Tn) {
    const int t = bid;
    row[k] = Wp[t * Hn + k];
    __syncthreads();
    float acc = 0.f;
#pragma unroll 8
    for (int h = 0; h < Hn; ++h) acc = fmaf(row[h], Wf[h * Hn + k], acc);
    M[t * Hn + k] = acc;
  } else if (bid < Tn + Nn) {
    const int n = bid - Tn;
    row[k] = node_emb[n * Hn + k];
    __syncthreads();
    float acc = 0.f;
#pragma unroll 8
    for (int h = 0; h < Hn; ++h) acc = fmaf(row[h], Wf[(Hn + h) * Hn + k], acc);
    __syncthreads();
    row[k] = bp[k];
    __syncthreads();
#pragma unroll 8
    for (int h = 0; h < Hn; ++h) acc = fmaf(row[h], Wf[h * Hn + k], acc);
    E[n * Hn + k] = acc;
  } else {
    const int t = bid - Tn - Nn;
    row[k] = time_emb[t * Hn + k];
    __syncthreads();
    float acc = bf[k];
#pragma unroll 8
    for (int h = 0; h < Hn; ++h) acc = fmaf(row[h], Wf[(2 * Hn + h) * Hn + k], acc);
    Ct[t * Hn + k] = acc;
  }
}

// XOR-butterfly step via ds_swizzle (BitMode: (xor<<10) | 0x1F) — stays within
// 16-lane row groups for masks 1,2,4,8. Avoids ds_bpermute + addr VALU.
__device__ __forceinline__ float swz_xor1(float v) {
  return __int_as_float(__builtin_amdgcn_ds_swizzle(__float_as_int(v), 0x041F));
}
__device__ __forceinline__ float swz_xor2(float v) {
  return __int_as_float(__builtin_amdgcn_ds_swizzle(__float_as_int(v), 0x081F));
}
__device__ __forceinline__ float swz_xor4(float v) {
  return __int_as_float(__builtin_amdgcn_ds_swizzle(__float_as_int(v), 0x101F));
}
__device__ __forceinline__ float swz_xor8(float v) {
  return __int_as_float(__builtin_amdgcn_ds_swizzle(__float_as_int(v), 0x201F));
}

// ---------------------------------------------------------------------------
// Main kernel: one block per (b,n). A row = x_row @ M + E[n] built in LDS.
// Each lane owns 8 columns (2x float4) -> a t-row spans 16 lanes; a wave
// handles 4 t-rows per iteration (2 KB stored). LayerNorm reduction = 4
// ds_swizzle XOR levels over 16 lanes. HBM-write-bound by design.
// ---------------------------------------------------------------------------
__global__ __launch_bounds__(256) void main_kernel(
    const float* __restrict__ x, const float* __restrict__ M,
    const float* __restrict__ E, const float* __restrict__ Ct,
    const float* __restrict__ gamma, const float* __restrict__ beta,
    float* __restrict__ out) {
  const int bn = blockIdx.x;        // b*N + n
  const int n = bn & (Nn - 1);      // N = 256 (pow2)
  __shared__ float xs[Tn];
  __shared__ __align__(16) float as[Hn];
  const int tid = threadIdx.x;

  if (tid < Tn) xs[tid] = x[bn * Tn + tid];
  __syncthreads();
  if (tid < Hn) {
    float acc = E[n * Hn + tid];
#pragma unroll 8
    for (int t = 0; t < Tn; ++t) acc = fmaf(xs[t], M[t * Hn + tid], acc);
    as[tid] = acc;
  }
  __syncthreads();

  const int wave = tid >> 6;
  const int lane = tid & 63;
  const int r  = lane >> 4;   // row-within-wave (0..3)
  const int cg = lane & 15;   // 16 column-groups of 8 floats
  const int cb = cg * 8;

  const float4 a0 = *(const float4*)&as[cb];
  const float4 a1 = *(const float4*)&as[cb + 4];
  const float4 g0 = *(const float4*)&gamma[cb];
  const float4 g1 = *(const float4*)&gamma[cb + 4];
  const float4 q0 = *(const float4*)&beta[cb];
  const float4 q1 = *(const float4*)&beta[cb + 4];
  const float inv128 = 1.f / 128.f;

#pragma unroll
  for (int i = 0; i < Tn / 16; ++i) {   // 6 iterations; rows i*16 .. i*16+15
    const int t = i * 16 + wave * 4 + r;
    const float4 c0 = *(const float4*)&Ct[t * Hn + cb];
    const float4 c1 = *(const float4*)&Ct[t * Hn + cb + 4];
    const float h0 = fmaxf(a0.x + c0.x, 0.f);
    const float h1 = fmaxf(a0.y + c0.y, 0.f);
    const float h2 = fmaxf(a0.z + c0.z, 0.f);
    const float h3 = fmaxf(a0.w + c0.w, 0.f);
    const float h4 = fmaxf(a1.x + c1.x, 0.f);
    const float h5 = fmaxf(a1.y + c1.y, 0.f);
    const float h6 = fmaxf(a1.z + c1.z, 0.f);
    const float h7 = fmaxf(a1.w + c1.w, 0.f);

    float s = ((h0 + h1) + (h2 + h3)) + ((h4 + h5) + (h6 + h7));
    float ss = h0 * h0;
    ss = fmaf(h1, h1, ss); ss = fmaf(h2, h2, ss); ss = fmaf(h3, h3, ss);
    ss = fmaf(h4, h4, ss); ss = fmaf(h5, h5, ss); ss = fmaf(h6, h6, ss);
    ss = fmaf(h7, h7, ss);

    s += swz_xor1(s);  ss += swz_xor1(ss);
    s += swz_xor2(s);  ss += swz_xor2(ss);
    s += swz_xor4(s);  ss += swz_xor4(ss);
    s += swz_xor8(s);  ss += swz_xor8(ss);

    const float mean = s * inv128;
    const float var  = fmaf(-mean, mean, ss * inv128);
    const float inv  = rsqrtf(var + EPSf);

    float4 o0, o1;
    o0.x = fmaf((h0 - mean) * inv, g0.x, q0.x);
    o0.y = fmaf((h1 - mean) * inv, g0.y, q0.y);
    o0.z = fmaf((h2 - mean) * inv, g0.z, q0.z);
    o0.w = fmaf((h3 - mean) * inv, g0.w, q0.w);
    o1.x = fmaf((h4 - mean) * inv, g1.x, q1.x);
    o1.y = fmaf((h5 - mean) * inv, g1.y, q1.y);
    o1.z = fmaf((h6 - mean) * inv, g1.z, q1.z);
    o1.w = fmaf((h7 - mean) * inv, g1.w, q1.w);

    float* op = &out[((size_t)bn * Tn + t) * Hn + cb];
    *(float4*)op = o0;
    *(float4*)(op + 4) = o1;
  }
}

extern "C" void kernel_launch(void* const* d_in, const int* in_sizes, int n_in,
                              void* d_out, int out_size, void* d_ws, size_t ws_size,
                              hipStream_t stream) {
  const float* x        = (const float*)d_in[0];
  const float* Wp       = (const float*)d_in[1];
  const float* bp       = (const float*)d_in[2];
  const float* Wf       = (const float*)d_in[3];
  const float* bf       = (const float*)d_in[4];
  const float* gamma    = (const float*)d_in[5];
  const float* beta     = (const float*)d_in[6];
  const float* node_emb = (const float*)d_in[7];
  const float* time_emb = (const float*)d_in[8];
  float* out = (float*)d_out;

  // Workspace layout (floats): M[96*128] | E[256*128] | Ct[96*128]  (~229 KB)
  float* ws = (float*)d_ws;
  float* M  = ws;
  float* E  = ws + Tn * Hn;
  float* Ct = ws + Tn * Hn + Nn * Hn;

  precompute_kernel<<<Tn + Nn + Tn, 128, 0, stream>>>(Wp, bp, Wf, bf, node_emb,
                                                      time_emb, M, E, Ct);
  main_kernel<<<Bn * Nn, 256, 0, stream>>>(x, M, E, Ct, gamma, beta, out);
}